// Round 12
// baseline (106.451 us; speedup 1.0000x reference)
//
#include <hip/hip_runtime.h>

// Problem constants (batch: (3, 1280, 1280) fp32, PATCH=16)
#define PS 16
#define HW 1280
#define NPS 80            // patches per side
#define NP (NPS * NPS)    // 6400 patches
#define GS 12             // floats per record: 9 gram + 1 sq + 2 pad (48B)

typedef float vf4 __attribute__((ext_vector_type(4)));

// ordered-uint mapping for float atomic max
__device__ __forceinline__ unsigned f2ord(float f) {
    unsigned u = __float_as_uint(f);
    return (u & 0x80000000u) ? ~u : (u | 0x80000000u);
}
__device__ __forceinline__ float ord2f(unsigned m) {
    return (m & 0x80000000u) ? __uint_as_float(m & 0x7FFFFFFFu) : __uint_as_float(~m);
}

// ---- gram: grid(1600) x 256; wave w computes patch blockIdx.x*4+w (r7 form).
__global__ __launch_bounds__(256) void gram_kernel(const float* __restrict__ x,
                                                   float* __restrict__ G,
                                                   unsigned* __restrict__ mm) {
    const int t = threadIdx.x;
    if (blockIdx.x == 0 && t == 0) mm[0] = 0u;  // max identity
    const int n = blockIdx.x * 4 + (t >> 6);
    const int l = t & 63;
    const int pi = n / NPS, pj = n % NPS;
    const int r = l >> 2, c = (l & 3) * 4;
    const size_t base = (size_t)(pi * PS + r) * HW + pj * PS + c;
    const float4 A = *(const float4*)(x + base);
    const float4 B = *(const float4*)(x + base + (size_t)HW * HW);
    const float4 C = *(const float4*)(x + base + 2 * (size_t)HW * HW);
    float p[6];
    p[0] = A.x * A.x + A.y * A.y + A.z * A.z + A.w * A.w;
    p[1] = A.x * B.x + A.y * B.y + A.z * B.z + A.w * B.w;
    p[2] = A.x * C.x + A.y * C.y + A.z * C.z + A.w * C.w;
    p[3] = B.x * B.x + B.y * B.y + B.z * B.z + B.w * B.w;
    p[4] = B.x * C.x + B.y * C.y + B.z * C.z + B.w * C.w;
    p[5] = C.x * C.x + C.y * C.y + C.z * C.z + C.w * C.w;
#pragma unroll
    for (int k = 0; k < 6; ++k) {
        float v = p[k];
#pragma unroll
        for (int off = 32; off; off >>= 1) v += __shfl_xor(v, off);
        p[k] = v;
    }
    if (l == 0) {
        const float sc = 1.0f / 768.0f;
        const float g0 = p[0] * sc, g1 = p[1] * sc, g2 = p[2] * sc;
        const float g3 = p[3] * sc, g4 = p[4] * sc, g5 = p[5] * sc;
        const float row[9] = {g0, g1, g2, g1, g3, g4, g2, g4, g5};
        float s = 0.f;
#pragma unroll
        for (int k = 0; k < 9; ++k) s = fmaf(row[k], row[k], s);
        float* dst = G + (size_t)n * GS;
        *(float4*)(dst)     = make_float4(row[0], row[1], row[2], row[3]);
        *(float4*)(dst + 4) = make_float4(row[4], row[5], row[6], row[7]);
        *(float4*)(dst + 8) = make_float4(row[8], s, 0.f, 0.f);
    }
}

// ---- max scan, upper triangle only. 6-dot form: LDS i-row holds
// {-2g00,-4g01,-4g02,-2g11,-4g12,-2g22, s, pad}; acc seeded with si+sj.
#define MI 64
#define MJ 256
__global__ __launch_bounds__(256) void max_kernel(const float* __restrict__ G,
                                                  unsigned* __restrict__ mm) {
    const int i0 = blockIdx.x * MI;
    const int j0 = blockIdx.y * MJ;
    if (i0 > j0 + MJ - 1) return;  // tile entirely below diagonal
    __shared__ float rg[MI * 8];
    __shared__ float smax[4];
    const int t = threadIdx.x;
    if (t < MI) {
        const float* src = G + (size_t)(i0 + t) * GS;
        const float4 a = *(const float4*)(src);
        const float4 b = *(const float4*)(src + 4);
        const float4 q = *(const float4*)(src + 8);
        float* d = rg + t * 8;
        d[0] = -2.f * a.x; d[1] = -4.f * a.y; d[2] = -4.f * a.z;
        d[3] = -2.f * b.x; d[4] = -4.f * b.y; d[5] = -2.f * q.x;
        d[6] = q.y; d[7] = 0.f;
    }
    __syncthreads();
    const int l = t & 63, w = t >> 6;
    const int j = j0 + l * 4;
    float gj[4][6], sj[4];
#pragma unroll
    for (int c = 0; c < 4; ++c) {
        const float* src = G + (size_t)(j + c) * GS;
        const float4 a = *(const float4*)(src);
        const float4 b = *(const float4*)(src + 4);
        const float4 q = *(const float4*)(src + 8);
        gj[c][0] = a.x; gj[c][1] = a.y; gj[c][2] = a.z;
        gj[c][3] = b.x; gj[c][4] = b.y; gj[c][5] = q.x;
        sj[c] = q.y;
    }
    float vmax = -3.4e38f;
#pragma unroll 4
    for (int rr = 0; rr < MI / 4; ++rr) {
        const int r = w * (MI / 4) + rr;
        const float4 A = *(const float4*)(rg + r * 8);
        const float4 B = *(const float4*)(rg + r * 8 + 4);
        const float si = B.z;
#pragma unroll
        for (int c = 0; c < 4; ++c) {
            float acc = si + sj[c];
            acc = fmaf(A.x, gj[c][0], acc);
            acc = fmaf(A.y, gj[c][1], acc);
            acc = fmaf(A.z, gj[c][2], acc);
            acc = fmaf(A.w, gj[c][3], acc);
            acc = fmaf(B.x, gj[c][4], acc);
            acc = fmaf(B.y, gj[c][5], acc);
            vmax = fmaxf(vmax, acc);
        }
    }
#pragma unroll
    for (int off = 32; off; off >>= 1) vmax = fmaxf(vmax, __shfl_xor(vmax, off));
    if ((t & 63) == 0) smax[w] = vmax;
    __syncthreads();
    if (t == 0) {
        const float bmax = fmaxf(fmaxf(smax[0], smax[1]), fmaxf(smax[2], smax[3]));
        atomicMax(mm, f2ord(bmax));
    }
}

// ---- normalized write (r7 geometry; 6-dot with inv folded into i-tile).
#define WI 16
__global__ __launch_bounds__(320) void write_kernel(const float* __restrict__ G,
                                                    const unsigned* __restrict__ mm,
                                                    float* __restrict__ out) {
    const int t = threadIdx.x;
    const int w = t >> 6, l = t & 63;
    const int i0 = blockIdx.y * WI;
    const int jw = blockIdx.x * 1280 + w * 256 + l * 4;  // lane's 4 cols
    const float inv = 1.f / ord2f(mm[0]);
    __shared__ float rg[WI * 8];
    if (t < WI) {
        const float* src = G + (size_t)(i0 + t) * GS;
        const float4 a = *(const float4*)(src);
        const float4 b = *(const float4*)(src + 4);
        const float4 q = *(const float4*)(src + 8);
        const float m2 = -2.f * inv, m4 = -4.f * inv;
        float* d = rg + t * 8;
        d[0] = m2 * a.x; d[1] = m4 * a.y; d[2] = m4 * a.z;
        d[3] = m2 * b.x; d[4] = m4 * b.y; d[5] = m2 * q.x;
        d[6] = inv * q.y; d[7] = 0.f;
    }
    float gj[4][6], bj[4];
#pragma unroll
    for (int c = 0; c < 4; ++c) {
        const float* src = G + (size_t)(jw + c) * GS;
        const float4 a = *(const float4*)(src);
        const float4 b = *(const float4*)(src + 4);
        const float4 q = *(const float4*)(src + 8);
        gj[c][0] = a.x; gj[c][1] = a.y; gj[c][2] = a.z;
        gj[c][3] = b.x; gj[c][4] = b.y; gj[c][5] = q.x;
        bj[c] = inv * q.y;
    }
    __syncthreads();
    float* dst = out + (size_t)i0 * NP + jw;
#pragma unroll 4
    for (int rr = 0; rr < WI; ++rr) {
        const float4 A = *(const float4*)(rg + rr * 8);
        const float4 B = *(const float4*)(rg + rr * 8 + 4);
        const float hi = B.z;
        vf4 dv;
#pragma unroll
        for (int c = 0; c < 4; ++c) {
            float acc = hi + bj[c];
            acc = fmaf(A.x, gj[c][0], acc);
            acc = fmaf(A.y, gj[c][1], acc);
            acc = fmaf(A.z, gj[c][2], acc);
            acc = fmaf(A.w, gj[c][3], acc);
            acc = fmaf(B.x, gj[c][4], acc);
            acc = fmaf(B.y, gj[c][5], acc);
            dv[c] = acc;
        }
        *(vf4*)dst = dv;
        dst += NP;
    }
}

extern "C" void kernel_launch(void* const* d_in, const int* in_sizes, int n_in,
                              void* d_out, int out_size, void* d_ws, size_t ws_size,
                              hipStream_t stream) {
    (void)in_sizes; (void)n_in; (void)out_size; (void)ws_size;
    const float* x = (const float*)d_in[0];
    float* out = (float*)d_out;
    float* G = (float*)d_ws;                                       // 300 KiB
    unsigned* mm = (unsigned*)((char*)d_ws + (size_t)NP * GS * sizeof(float));

    // ATTRIBUTION: gram and max each dispatched 3x (idempotent: gram rewrites
    // identical G and re-resets mm BEFORE any max runs; repeated atomicMax is
    // a no-op). gram+max = (dur_r12 - dur_r13_single)/2.
    gram_kernel<<<NP / 4, 256, 0, stream>>>(x, G, mm);
    gram_kernel<<<NP / 4, 256, 0, stream>>>(x, G, mm);
    gram_kernel<<<NP / 4, 256, 0, stream>>>(x, G, mm);
    max_kernel<<<dim3(NP / MI, NP / MJ), 256, 0, stream>>>(G, mm);
    max_kernel<<<dim3(NP / MI, NP / MJ), 256, 0, stream>>>(G, mm);
    max_kernel<<<dim3(NP / MI, NP / MJ), 256, 0, stream>>>(G, mm);
    write_kernel<<<dim3(5, NP / WI), 320, 0, stream>>>(G, mm, out);
}